// Round 6
// baseline (334.618 us; speedup 1.0000x reference)
//
#include <hip/hip_runtime.h>

// DeltaModulationEncoder: x (16, 256, 8192) f32 -> spikes {-1,0,1} f32.
// Exact monolithic scan (recurrence is serial per channel).
//
// Round-5 post-mortem: LDS staging via global_load_lds serialized on
// compiler-inserted waits (the DMA builtin is a conservative LDS clobber, so
// every ds_read was ordered behind ALL outstanding vmem incl. store acks:
// ~380 cyc x 32 chunks x 64 tiles ~= the whole measured runtime).
// This version has NO LDS at all: per-lane global_load_dwordx4 into a 16-deep
// register pipeline. Plain VGPR loads are what hipcc pipelines natively with
// counted s_waitcnt vmcnt(N); each chunk's load issues 16 chunks (~1200 cyc)
// before first use, covering cold-HBM latency (~900 cyc).
//
// 256 blocks x 1 wave; lanes 0-15 each own one channel (16 ch/block).
// Stores are per-lane dwordx4, fire-and-forget (never waited on).

constexpr float TH   = 0.1f;
constexpr int   T    = 8192;
constexpr int   NCH  = 4096;
constexpr int   CPB  = 16;            // channels per block
constexpr int   NBLK = NCH / CPB;     // 256 blocks (one per CU)
constexpr int   NC   = T / 4;         // 2048 float4 chunks per channel
constexpr int   PF   = 16;            // prefetch depth == unroll (indices static)

// Bit-exact reference step. Reference: err = x - recon; net = (err>th)-(err<-th);
// recon += net*th; spike = net. net*th is exactly {+0.1f,-0.1f,+0.0f}, so
// recon_next is exactly one of {fl(recon+0.1f), fl(recon-0.1f), recon}
// (recon is never -0.0f: equal-magnitude f32 subtraction yields +0.0f, so the
// net==0 case recon+0.0f == recon bitwise). rp/rm are computed OFF the
// dependency chain; the chain is sub -> cmp -> cndmask -> cndmask ~= 16 cyc.
// c1 and c2 are mutually exclusive. No mul feeds an add -> FMA contraction
// cannot change rounding. Spikes selected as inline-constant {-1,0,1}.
__device__ __forceinline__ void dm_step(float xv, float& recon, float& spike) {
    float rp  = recon + TH;        // off-chain
    float rm  = recon - TH;        // off-chain
    float err = xv - recon;        // chain
    bool  c1  = err > TH;          // chain (c1,c2 both depend only on err)
    bool  c2  = err < -TH;
    float rn  = c1 ? rp : recon;   // chain
    rn        = c2 ? rm : rn;      // chain
    float sp  = c1 ? 1.0f : 0.0f;  // off-chain
    spike     = c2 ? -1.0f : sp;   // off-chain
    recon     = rn;
}

__device__ __forceinline__ void proc4(const float4 c, float& recon, float4& s) {
    dm_step(c.x, recon, s.x);
    dm_step(c.y, recon, s.y);
    dm_step(c.z, recon, s.z);
    dm_step(c.w, recon, s.w);
}

__global__ __launch_bounds__(64) void dm_scan(const float* __restrict__ x,
                                              float* __restrict__ out) {
    const int lane = threadIdx.x;
    if (lane >= CPB) return;                      // lanes 16-63 idle (exec-masked)
    const int ch = blockIdx.x * CPB + lane;

    const float4* __restrict__ pin = (const float4*)(x   + (size_t)ch * T);
    float4*       __restrict__ po  = (float4*)      (out + (size_t)ch * T);

    // 16-deep register pipeline. PF == UNROLL, so q[] indices are always
    // compile-time constants (registers, not scratch — rule #20).
    float4 q[PF];
#pragma unroll
    for (int i = 0; i < PF; ++i) q[i] = pin[i];

    float recon = 0.0f;

    // Main loop: (NC - PF) = 2032 chunks = 127 groups of 16.
    for (int base = 0; base < NC - PF; base += PF) {
#pragma unroll
        for (int j = 0; j < PF; ++j) {
            const int c  = base + j;
            float4    xv = q[j];
            q[j] = pin[c + PF];      // refill slot: 16 chunks ahead of its use
            float4 s;
            proc4(xv, recon, s);
            po[c] = s;               // fire-and-forget
        }
    }

    // Epilogue: last PF chunks, no prefetch.
#pragma unroll
    for (int j = 0; j < PF; ++j) {
        const int c  = (NC - PF) + j;
        float4    xv = q[j];
        float4 s;
        proc4(xv, recon, s);
        po[c] = s;
    }
}

extern "C" void kernel_launch(void* const* d_in, const int* in_sizes, int n_in,
                              void* d_out, int out_size, void* d_ws, size_t ws_size,
                              hipStream_t stream) {
    const float* x   = (const float*)d_in[0];
    float*       out = (float*)d_out;
    dm_scan<<<NBLK, 64, 0, stream>>>(x, out);
}

// Round 7
// 307.794 us; speedup vs baseline: 1.0871x; 1.0871x over previous
//
#include <hip/hip_runtime.h>

// DeltaModulationEncoder: x (16, 256, 8192) f32 -> spikes {-1,0,1} f32.
// Exact monolithic scan (recurrence is serial per channel).
//
// Round-6 post-mortem: VGPR_Count=68 proved the register pipeline was
// collapsed by the allocator (no occupancy floor declared -> hipcc clamps
// VGPRs, loads land next to uses, every chunk eats a full memory round-trip).
// Round-5 post-mortem: global_load_lds is modeled as an LDS clobber -> ds
// reads serialized behind all vmem (incl. store acks).
//
// This version:
//   - __launch_bounds__(64, 1): VGPR budget up to 512, pipeline survives.
//   - Manual reg->LDS staging (no global_load_lds): coalesced
//     global_load_dwordx4 -> q[8] -> ds_write_b128 into a padded double
//     buffer. Compiler expresses the dependency with counted vmcnt/lgkmcnt.
//   - Loads for tile t+2 issued a full tile (~2 kcyc) before their ds_write.
//   - The wait before ds_write is vmcnt(32): 8 loads are older than the 32
//     fire-and-forget stores -> stores never drain.
//   - sched_barrier(0) after compute keeps the scheduler from hoisting the
//     staging wait above the compute phase.
//   - ROWF=132 pad: ds_write_b128 2-way (free), ds_read_b128 conflict-free.
// 256 blocks x 1 wave; lanes 0-15 each own one channel; all 64 lanes stage.

constexpr float TH     = 0.1f;
constexpr int   T      = 8192;
constexpr int   NCH    = 4096;
constexpr int   CPB    = 16;             // channels per block
constexpr int   NBLK   = NCH / CPB;      // 256 blocks (one per CU)
constexpr int   TILE   = 128;            // timesteps per staged tile
constexpr int   NTILE  = T / TILE;       // 64
constexpr int   NCHUNK = TILE / 4;       // 32 float4 chunks per row-tile
constexpr int   ROWF   = TILE + 4;       // 132: 16B-aligned rows, no conflicts
constexpr int   NLD    = CPB * TILE / (64 * 4);  // 8 loads/lane/tile

// Bit-exact reference step. Reference: err = x - recon; net = (err>th)-(err<-th);
// recon += net*th; spike = net. net*th is exactly {+0.1f,-0.1f,+0.0f}, so
// recon_next is exactly one of {fl(recon+0.1f), fl(recon-0.1f), recon}
// (recon is never -0.0f, so the net==0 case recon+0.0f == recon bitwise).
// rp/rm are computed OFF the dependency chain; chain = sub->cmp->sel->sel.
// No mul feeds an add -> FMA contraction cannot change rounding.
__device__ __forceinline__ void dm_step(float xv, float& recon, float& spike) {
    float rp  = recon + TH;        // off-chain
    float rm  = recon - TH;        // off-chain
    float err = xv - recon;        // chain
    bool  c1  = err > TH;
    bool  c2  = err < -TH;
    float rn  = c1 ? rp : recon;   // chain
    rn        = c2 ? rm : rn;      // chain
    float sp  = c1 ? 1.0f : 0.0f;  // off-chain
    spike     = c2 ? -1.0f : sp;   // off-chain
    recon     = rn;
}

__global__ __launch_bounds__(64, 1) void dm_scan(const float* __restrict__ x,
                                                 float* __restrict__ out) {
    __shared__ float xb[2][CPB][ROWF];   // 16.9 KiB, double-buffered
    const int lane   = threadIdx.x;
    const int chBase = blockIdx.x * CPB;

    // Staging map, instruction i (0..7): global row r = 2i + (lane>>5),
    // float4 col s = lane&31. Each instr covers 2 rows x 512B contiguous.
    const int r_i0 = (lane >> 5);        // 0 or 1
    const int s_c  = (lane & 31);        // float4 index within row
    const float* gbase = x + (size_t)chBase * T + (size_t)r_i0 * T + 4 * s_c;

    float4 q[NLD];
    auto gload = [&](int t) {
        const float* bt = gbase + (size_t)t * TILE;
#pragma unroll
        for (int i = 0; i < NLD; ++i) {
            q[i] = *(const float4*)(bt + (size_t)(2 * i) * T);
        }
    };
    auto ldswrite = [&](int b) {
#pragma unroll
        for (int i = 0; i < NLD; ++i) {
            *(float4*)&xb[b][2 * i + r_i0][4 * s_c] = q[i];
        }
    };

    float recon = 0.0f;
    float4* po = (float4*)(out + (size_t)(chBase + (lane & (CPB - 1))) * T);

    // Prologue: tile 0 staged, tile 1's loads in flight.
    gload(0);
    ldswrite(0);            // compiler: s_waitcnt vmcnt(0) before first dsw
    gload(1);

    for (int t = 0; t < NTILE; ++t) {
        const int b = t & 1;

        // Compute tile t from LDS[b] (first ds_read waits lgkmcnt on the
        // ds_writes; ~120 cyc once per tile). 3-deep ds_read pipeline, full
        // unroll -> static indices (registers).
        if (lane < CPB) {
            const float4* row = (const float4*)&xb[b][lane][0];
            float4* pot = po + (size_t)t * NCHUNK;
            float4 d[3];
            d[0] = row[0];
            d[1] = row[1];
#pragma unroll
            for (int c = 0; c < NCHUNK; ++c) {
                float4 xv = d[c % 3];
                if (c + 2 < NCHUNK) d[(c + 2) % 3] = row[c + 2];
                float4 s;
                dm_step(xv.x, recon, s.x);
                dm_step(xv.y, recon, s.y);
                dm_step(xv.z, recon, s.z);
                dm_step(xv.w, recon, s.w);
                pot[c] = s;            // fire-and-forget
            }
        }

        // Keep the staging wait out of the compute phase.
        __builtin_amdgcn_sched_barrier(0);

        if (t + 1 < NTILE) {
            // q = tile t+1 (issued one full tile ago). Compiler waits
            // vmcnt(32): 8 loads are the oldest ops, 32 stores younger.
            ldswrite(b ^ 1);
        }
        if (t + 2 < NTILE) {
            gload(t + 2);   // a full tile of compute before its ds_write
        }
    }
}

extern "C" void kernel_launch(void* const* d_in, const int* in_sizes, int n_in,
                              void* d_out, int out_size, void* d_ws, size_t ws_size,
                              hipStream_t stream) {
    const float* x   = (const float*)d_in[0];
    float*       out = (float*)d_out;
    dm_scan<<<NBLK, 64, 0, stream>>>(x, out);
}

// Round 8
// 273.442 us; speedup vs baseline: 1.2237x; 1.1256x over previous
//
#include <hip/hip_runtime.h>

// DeltaModulationEncoder: x (16, 256, 8192) f32 -> spikes {-1,0,1} f32.
// Exact monolithic scan (recurrence is serial per channel).
//
// Model from rounds 3-7: wall = 8192 x R cyc, R = per-step latency. All
// variants measured R ~= 84-100; chain floor is ~16-20. The excess is exposed
// memory latency per step. R6's pure-register pipeline was the right idea but
// provably collapsed in regalloc (VGPR_Count=68 < 64 needed for q[] alone;
// no min-waves bound declared). This version makes it un-collapsible:
//   - __launch_bounds__(64, 1): full VGPR budget, occupancy floor 1 wave/EU.
//   - Ping-pong groups qA[16]/qB[16] (128 VGPRs of data), every index
//     compile-time (rule #20) -> registers, not scratch.
//   - sched_barrier(0) between {load group g+1} and {compute group g}: the
//     scheduler can neither sink the loads into compute nor hoist the
//     compute's s_waitcnt above the load issue. Lookahead 16-32 chunks
//     (~1.3-2.5 kcyc) >> HBM latency (~900 cyc); waits are counted vmcnt.
//   - No LDS anywhere (round-5/7 lesson: LDS staging paths serialize on
//     compiler-inserted ds/vmem ordering).
// 256 blocks x 1 wave; lanes 0-15 each own one channel. Stores per-lane
// dwordx4, fire-and-forget (never waited on).

constexpr float TH   = 0.1f;
constexpr int   T    = 8192;
constexpr int   NCH  = 4096;
constexpr int   CPB  = 16;            // channels per block
constexpr int   NBLK = NCH / CPB;     // 256 blocks (one per CU)
constexpr int   NC   = T / 4;         // 2048 float4 chunks per channel
constexpr int   PF   = 16;            // chunks per ping-pong group

// Bit-exact reference step. Reference: err = x - recon; net = (err>th)-(err<-th);
// recon += net*th; spike = net. net*th is exactly {+0.1f,-0.1f,+0.0f}, so
// recon_next is exactly one of {fl(recon+0.1f), fl(recon-0.1f), recon}
// (recon is never -0.0f, so the net==0 case recon+0.0f == recon bitwise).
// rp/rm are computed OFF the dependency chain; chain = sub->cmp->sel->sel.
// c1,c2 mutually exclusive. No mul feeds an add -> FMA contraction can't
// change rounding. Spikes selected as inline-constant {-1.0f, 0.0f, 1.0f}.
__device__ __forceinline__ void dm_step(float xv, float& recon, float& spike) {
    float rp  = recon + TH;        // off-chain
    float rm  = recon - TH;        // off-chain
    float err = xv - recon;        // chain
    bool  c1  = err > TH;
    bool  c2  = err < -TH;
    float rn  = c1 ? rp : recon;   // chain
    rn        = c2 ? rm : rn;      // chain
    float sp  = c1 ? 1.0f : 0.0f;  // off-chain
    spike     = c2 ? -1.0f : sp;   // off-chain
    recon     = rn;
}

__device__ __forceinline__ void proc4(const float4 c, float& recon, float4& s) {
    dm_step(c.x, recon, s.x);
    dm_step(c.y, recon, s.y);
    dm_step(c.z, recon, s.z);
    dm_step(c.w, recon, s.w);
}

__global__ __launch_bounds__(64, 1) void dm_scan(const float* __restrict__ x,
                                                 float* __restrict__ out) {
    const int lane = threadIdx.x;
    if (lane >= CPB) return;                 // lanes 16-63 idle
    const int ch = blockIdx.x * CPB + lane;

    const float4* __restrict__ pin = (const float4*)(x   + (size_t)ch * T);
    float4*       __restrict__ po  = (float4*)      (out + (size_t)ch * T);

    float4 qA[PF], qB[PF];                   // named arrays: indices static
#pragma unroll
    for (int i = 0; i < PF; ++i) qA[i] = pin[i];

    float recon = 0.0f;

    // 64 iterations; each handles two PF-chunk groups (A then B).
    for (int base = 0; base < NC; base += 2 * PF) {
        // Load group B = [base+PF, base+2PF)  (always in range: base<=2016).
#pragma unroll
        for (int i = 0; i < PF; ++i) qB[i] = pin[base + PF + i];
        __builtin_amdgcn_sched_barrier(0);

        // Compute group A = [base, base+PF). Its loads were issued one full
        // group (~16 chunks) ago; wait here is counted vmcnt (B outstanding).
#pragma unroll
        for (int j = 0; j < PF; ++j) {
            float4 s;
            proc4(qA[j], recon, s);
            po[base + j] = s;                // fire-and-forget
        }
        __builtin_amdgcn_sched_barrier(0);

        // Reload group A = [base+2PF, base+3PF) for the next iteration.
        if (base + 2 * PF < NC) {
#pragma unroll
            for (int i = 0; i < PF; ++i) qA[i] = pin[base + 2 * PF + i];
        }
        __builtin_amdgcn_sched_barrier(0);

        // Compute group B.
#pragma unroll
        for (int j = 0; j < PF; ++j) {
            float4 s;
            proc4(qB[j], recon, s);
            po[base + PF + j] = s;
        }
        __builtin_amdgcn_sched_barrier(0);
    }
}

extern "C" void kernel_launch(void* const* d_in, const int* in_sizes, int n_in,
                              void* d_out, int out_size, void* d_ws, size_t ws_size,
                              hipStream_t stream) {
    const float* x   = (const float*)d_in[0];
    float*       out = (float*)d_out;
    dm_scan<<<NBLK, 64, 0, stream>>>(x, out);
}